// Round 13
// baseline (91.806 us; speedup 1.0000x reference)
//
#include <hip/hip_runtime.h>

// MountainCar batched rollout: B=8192 envs, 500 sequential steps of a
// 2->64->1 MLP policy + dynamics.
//
// Round 13 = R7 (proven best, 83.6us) + three chain/arbitration micro-cuts:
//  (1) asymmetric wave priority: even waves setprio(1) once -> stable
//      fast/filler role split between the 2 co-resident waves per SIMD
//  (2) dual-chain layer-2 accumulation (+1 instr, -12 cyc critical path;
//      NOT bundled with R6's DPP doubling which caused its regression)
//  (3) v2 computed from q directly: v1+0.0015-0.003q (u1's fma off the
//      v2 chain; v1+0.0015 issues while rcp is in flight)
// Model (12 rounds): wall/step = max(2*I, I+C)+eps; I~157, C~150-200.
// W=2 KL=16 is chain/granularity-bound at 402 cyc/step vs 314 issue floor.
// All structural alternatives measured worse (R5/R9 W=1 ILP, R10 W=4,
// R11 concentration, R12 stagger).

constexpr int B = 8192;
constexpr int L = 64;
constexpr int MAX_STEPS = 500;
constexpr float GOAL_P = 0.5f;
constexpr float MIN_P  = -1.2f;
constexpr float MIN_V  = -0.07f;
constexpr float MAX_V  = 0.07f;

constexpr int KL  = 16;       // lanes per env
constexpr int UPL = L / KL;   // hidden units per lane = 4

template<int CTRL>
__device__ __forceinline__ float dpp_add(float x) {
  int y = __builtin_amdgcn_update_dpp(0, __float_as_int(x), CTRL, 0xf, 0xf, true);
  return x + __int_as_float(y);
}

__global__ __launch_bounds__(256) void mc_kernel(
    const float* __restrict__ x,  const float* __restrict__ w1,
    const float* __restrict__ b1, const float* __restrict__ w2,
    const float* __restrict__ b2, float* __restrict__ out)
{
  int tid  = blockIdx.x * blockDim.x + threadIdx.x;
  int env  = tid >> 4;                 // env index
  int sub  = tid & 15;                 // lane-within-env
  int lane = threadIdx.x & 63;         // lane-within-wave

  constexpr float TS = 2.8853900817779268f;  // 2*log2(e), folded into w2/b2

  float w1a[UPL], w1b[UPL], b1r[UPL], w2r[UPL];
  const int j0 = sub * UPL;
#pragma unroll
  for (int i = 0; i < UPL; ++i) {
    w1a[i] = w1[j0 + i];          // w1[0][j]
    w1b[i] = w1[L + j0 + i];      // w1[1][j]
    b1r[i] = b1[j0 + i];
    w2r[i] = w2[j0 + i] * TS;     // w2[j][0], pre-scaled
  }
  const float b2seed = (sub == 0) ? b2[0] * TS : 0.0f;

  float4 st = reinterpret_cast<const float4*>(x)[env];
  const float r0 = st.w;
  float p = st.x, v = st.y, u = st.z;
  float racc = 0.0f;   // sum of u^2 over live steps

  unsigned long long live = __ballot(true);

  // (1) Stable wave-role split: even waves get elevated priority so the
  // SIMD arbiter always advances one designated wave when both are ready;
  // the other becomes the gap-filler. One SALU instr, outside the loop.
  if (((threadIdx.x >> 6) & 1) == 0) {
    __builtin_amdgcn_s_setprio(1);
  }

  for (int stp = 0; stp < MAX_STEPS; ++stp) {
    float p1 = fmaxf(p, MIN_P);
    float v1 = (p <= MIN_P) ? 0.0f : v;

    // cos(3*p1): v_cos takes revolutions; independent of the MLP chain.
    float c = __builtin_amdgcn_cosf(p1 * 0.47746482927568601f);

    // Layer 1 (relu).
    float h0 = fmaxf(fmaf(v1, w1b[0], fmaf(p1, w1a[0], b1r[0])), 0.0f);
    float h1 = fmaxf(fmaf(v1, w1b[1], fmaf(p1, w1a[1], b1r[1])), 0.0f);
    float h2 = fmaxf(fmaf(v1, w1b[2], fmaf(p1, w1a[2], b1r[2])), 0.0f);
    float h3 = fmaxf(fmaf(v1, w1b[3], fmaf(p1, w1a[3], b1r[3])), 0.0f);

    // (2) Layer 2: dual accumulation chains (depth 2 fma + add vs 4 fma).
    float se = fmaf(h2, w2r[2], fmaf(h0, w2r[0], b2seed));
    float so = fmaf(h3, w2r[3], h1 * w2r[1]);
    float s  = se + so;

    // 16-lane butterfly; every lane ends with the full pre-scaled logit.
    s = dpp_add<0xB1>(s);     // quad_perm [1,0,3,2] : + lane^1
    s = dpp_add<0x4E>(s);     // quad_perm [2,3,0,1] : + lane^2
    s = dpp_add<0x141>(s);    // row_half_mirror    : + lane^(4..7)
    s = dpp_add<0x140>(s);    // row_mirror         : + lane^(8..15)

    // tanh via q = 1/(exp2(s)+1):  u1 = 1-2q (for racc/output);
    // (3) v2 uses q directly: v1 + 0.0015*(1-2q) = (v1+0.0015) - 0.003q,
    // so u1's fma is off the v2 critical path and (v1+0.0015) issues
    // while the rcp is still in flight.
    float e  = __builtin_amdgcn_exp2f(s);
    float q  = __builtin_amdgcn_rcpf(e + 1.0f);
    float u1 = fmaf(-2.0f, q, 1.0f);

    float v2 = fmaf(-0.0025f, c, fmaf(-0.003f, q, v1 + 0.0015f));
    v2 = __builtin_amdgcn_fmed3f(v2, MIN_V, MAX_V);

    // Unconditional state update (write-at-crossing).
    p = p1 + v2;
    v = v2;
    u = u1;
    racc = fmaf(u1, u1, racc);

    // Newly-crossed envs commit their final row immediately.
    unsigned long long crossed = __ballot(p > GOAL_P) & live;
    if (crossed) {                        // wave-uniform, rarely taken
      live &= ~crossed;
      if (((crossed >> lane) & 1ull) && sub == 0) {
        float rout = fmaf(-0.1f, racc, r0) + 100.0f;
        reinterpret_cast<float4*>(out)[env] = make_float4(p, v, u, rout);
      }
      if (!live) return;                  // all 4 envs in wave committed
    }
  }

  // Envs that never crossed within MAX_STEPS: no +100.
  if (((live >> lane) & 1ull) && sub == 0) {
    float rout = fmaf(-0.1f, racc, r0);
    reinterpret_cast<float4*>(out)[env] = make_float4(p, v, u, rout);
  }
}

extern "C" void kernel_launch(void* const* d_in, const int* in_sizes, int n_in,
                              void* d_out, int out_size, void* d_ws, size_t ws_size,
                              hipStream_t stream) {
  const float* x  = (const float*)d_in[0];
  const float* w1 = (const float*)d_in[1];
  const float* b1 = (const float*)d_in[2];
  const float* w2 = (const float*)d_in[3];
  const float* b2 = (const float*)d_in[4];
  float* out = (float*)d_out;

  constexpr int threads = B * KL;  // 131072 -> 2048 waves -> 2 waves/SIMD
  mc_kernel<<<threads / 256, 256, 0, stream>>>(x, w1, b1, w2, b2, out);
}

// Round 14
// 90.274 us; speedup vs baseline: 1.0170x; 1.0170x over previous
//
#include <hip/hip_runtime.h>

// MountainCar batched rollout: B=8192 envs, 500 sequential steps of a
// 2->64->1 MLP policy + dynamics.
//
// Round 14 = R7 (proven best, 83.6us) + R13's chain cuts, WITHOUT R13's
// asymmetric setprio (isolated culprit: starving the low-prio wave broke
// 2-wave round-robin bubble filling -> VALUBusy 75->71, +8us).
//  - dual-chain layer-2 accumulation (+1 instr, -12 cyc critical path)
//  - v2 from q directly: (v1+0.0015) - 0.003q - 0.0025c (u1's fma off
//    the v2 critical path; v1+0.0015 issues while rcp is in flight)
// Model (13 rounds): wall/step = max(2*I, I+C); I~157, C~150-200.
// If this is null, ~83us is the structural floor (latency-bound recurrent
// chain, 2 waves/SIMD, serial C unhidable) -> declare ceiling.

constexpr int B = 8192;
constexpr int L = 64;
constexpr int MAX_STEPS = 500;
constexpr float GOAL_P = 0.5f;
constexpr float MIN_P  = -1.2f;
constexpr float MIN_V  = -0.07f;
constexpr float MAX_V  = 0.07f;

constexpr int KL  = 16;       // lanes per env
constexpr int UPL = L / KL;   // hidden units per lane = 4

template<int CTRL>
__device__ __forceinline__ float dpp_add(float x) {
  int y = __builtin_amdgcn_update_dpp(0, __float_as_int(x), CTRL, 0xf, 0xf, true);
  return x + __int_as_float(y);
}

__global__ __launch_bounds__(256) void mc_kernel(
    const float* __restrict__ x,  const float* __restrict__ w1,
    const float* __restrict__ b1, const float* __restrict__ w2,
    const float* __restrict__ b2, float* __restrict__ out)
{
  int tid  = blockIdx.x * blockDim.x + threadIdx.x;
  int env  = tid >> 4;                 // env index
  int sub  = tid & 15;                 // lane-within-env
  int lane = threadIdx.x & 63;         // lane-within-wave

  constexpr float TS = 2.8853900817779268f;  // 2*log2(e), folded into w2/b2

  float w1a[UPL], w1b[UPL], b1r[UPL], w2r[UPL];
  const int j0 = sub * UPL;
#pragma unroll
  for (int i = 0; i < UPL; ++i) {
    w1a[i] = w1[j0 + i];          // w1[0][j]
    w1b[i] = w1[L + j0 + i];      // w1[1][j]
    b1r[i] = b1[j0 + i];
    w2r[i] = w2[j0 + i] * TS;     // w2[j][0], pre-scaled
  }
  const float b2seed = (sub == 0) ? b2[0] * TS : 0.0f;

  float4 st = reinterpret_cast<const float4*>(x)[env];
  const float r0 = st.w;
  float p = st.x, v = st.y, u = st.z;
  float racc = 0.0f;   // sum of u^2 over live steps

  unsigned long long live = __ballot(true);

  for (int stp = 0; stp < MAX_STEPS; ++stp) {
    float p1 = fmaxf(p, MIN_P);
    float v1 = (p <= MIN_P) ? 0.0f : v;

    // cos(3*p1): v_cos takes revolutions; independent of the MLP chain.
    float c = __builtin_amdgcn_cosf(p1 * 0.47746482927568601f);

    // Layer 1 (relu).
    float h0 = fmaxf(fmaf(v1, w1b[0], fmaf(p1, w1a[0], b1r[0])), 0.0f);
    float h1 = fmaxf(fmaf(v1, w1b[1], fmaf(p1, w1a[1], b1r[1])), 0.0f);
    float h2 = fmaxf(fmaf(v1, w1b[2], fmaf(p1, w1a[2], b1r[2])), 0.0f);
    float h3 = fmaxf(fmaf(v1, w1b[3], fmaf(p1, w1a[3], b1r[3])), 0.0f);

    // Layer 2: dual accumulation chains (depth 2 fma + add vs 4 fma).
    float se = fmaf(h2, w2r[2], fmaf(h0, w2r[0], b2seed));
    float so = fmaf(h3, w2r[3], h1 * w2r[1]);
    float s  = se + so;

    // 16-lane butterfly; every lane ends with the full pre-scaled logit.
    s = dpp_add<0xB1>(s);     // quad_perm [1,0,3,2] : + lane^1
    s = dpp_add<0x4E>(s);     // quad_perm [2,3,0,1] : + lane^2
    s = dpp_add<0x141>(s);    // row_half_mirror    : + lane^(4..7)
    s = dpp_add<0x140>(s);    // row_mirror         : + lane^(8..15)

    // tanh via q = 1/(exp2(s)+1); u1 = 1-2q (racc/output only).
    // v2 from q directly: (v1+0.0015) - 0.003q - 0.0025c keeps u1's fma
    // off the v2 chain; (v1+0.0015) issues while the rcp is in flight.
    float e  = __builtin_amdgcn_exp2f(s);
    float q  = __builtin_amdgcn_rcpf(e + 1.0f);
    float u1 = fmaf(-2.0f, q, 1.0f);

    float v2 = fmaf(-0.0025f, c, fmaf(-0.003f, q, v1 + 0.0015f));
    v2 = __builtin_amdgcn_fmed3f(v2, MIN_V, MAX_V);

    // Unconditional state update (write-at-crossing).
    p = p1 + v2;
    v = v2;
    u = u1;
    racc = fmaf(u1, u1, racc);

    // Newly-crossed envs commit their final row immediately.
    unsigned long long crossed = __ballot(p > GOAL_P) & live;
    if (crossed) {                        // wave-uniform, rarely taken
      live &= ~crossed;
      if (((crossed >> lane) & 1ull) && sub == 0) {
        float rout = fmaf(-0.1f, racc, r0) + 100.0f;
        reinterpret_cast<float4*>(out)[env] = make_float4(p, v, u, rout);
      }
      if (!live) return;                  // all 4 envs in wave committed
    }
  }

  // Envs that never crossed within MAX_STEPS: no +100.
  if (((live >> lane) & 1ull) && sub == 0) {
    float rout = fmaf(-0.1f, racc, r0);
    reinterpret_cast<float4*>(out)[env] = make_float4(p, v, u, rout);
  }
}

extern "C" void kernel_launch(void* const* d_in, const int* in_sizes, int n_in,
                              void* d_out, int out_size, void* d_ws, size_t ws_size,
                              hipStream_t stream) {
  const float* x  = (const float*)d_in[0];
  const float* w1 = (const float*)d_in[1];
  const float* b1 = (const float*)d_in[2];
  const float* w2 = (const float*)d_in[3];
  const float* b2 = (const float*)d_in[4];
  float* out = (float*)d_out;

  constexpr int threads = B * KL;  // 131072 -> 2048 waves -> 2 waves/SIMD
  mc_kernel<<<threads / 256, 256, 0, stream>>>(x, w1, b1, w2, b2, out);
}

// Round 15
// 84.045 us; speedup vs baseline: 1.0923x; 1.0741x over previous
//
#include <hip/hip_runtime.h>

// MountainCar batched rollout: B=8192 envs, 500 sequential steps of a
// 2->64->1 MLP policy + dynamics.
//
// FINAL (= Round 7, measured optimum 83.6us over 14 rounds of search).
// Structure: KL=16 lanes/env, 2048 waves = 2 waves/SIMD (optimal: W=1
// stalls 55% [R1/R9], W=4 doubles issue [R10]); weights VGPR-resident;
// intrinsic DPP 4-stage butterfly (compiler owns the GFX9 VALU->DPP
// hazard; raw asm DPP failed [R3]); sign-free tanh 1-2/(exp2(k*s)+1) with
// k=2log2e folded into w2/b2; b2 seeded on lane 0; write-at-crossing (no
// per-step state merges; crossed envs commit immediately, dead envs
// compute bounded garbage); deferred -0.1 reward scale; med3 v-clip.
// Measured-worse variants: pk-f32 packing (R8/R9: -19k busy cyc, wall
// unchanged -> not issue-bound), 512-blocks (R11: lockstep waves),
// s_sleep stagger (R12: null), setprio asym (R13: breaks round-robin),
// dual-chain L2 + v2-from-q (R14: scheduling perturbation).
// Floor model: wall/step 402 cyc = issue 314 + ~90 unhidable serial-chain
// residue; HBM 0.03%, VALUBusy 75% -- latency-structure bound.

constexpr int B = 8192;
constexpr int L = 64;
constexpr int MAX_STEPS = 500;
constexpr float GOAL_P = 0.5f;
constexpr float MIN_P  = -1.2f;
constexpr float MIN_V  = -0.07f;
constexpr float MAX_V  = 0.07f;

constexpr int KL  = 16;       // lanes per env
constexpr int UPL = L / KL;   // hidden units per lane = 4

template<int CTRL>
__device__ __forceinline__ float dpp_add(float x) {
  int y = __builtin_amdgcn_update_dpp(0, __float_as_int(x), CTRL, 0xf, 0xf, true);
  return x + __int_as_float(y);
}

__global__ __launch_bounds__(256) void mc_kernel(
    const float* __restrict__ x,  const float* __restrict__ w1,
    const float* __restrict__ b1, const float* __restrict__ w2,
    const float* __restrict__ b2, float* __restrict__ out)
{
  int tid  = blockIdx.x * blockDim.x + threadIdx.x;
  int env  = tid >> 4;                 // env index
  int sub  = tid & 15;                 // lane-within-env
  int lane = threadIdx.x & 63;         // lane-within-wave

  constexpr float TS = 2.8853900817779268f;  // 2*log2(e), folded into w2/b2

  float w1a[UPL], w1b[UPL], b1r[UPL], w2r[UPL];
  const int j0 = sub * UPL;
#pragma unroll
  for (int i = 0; i < UPL; ++i) {
    w1a[i] = w1[j0 + i];          // w1[0][j]
    w1b[i] = w1[L + j0 + i];      // w1[1][j]
    b1r[i] = b1[j0 + i];
    w2r[i] = w2[j0 + i] * TS;     // w2[j][0], pre-scaled
  }
  const float b2seed = (sub == 0) ? b2[0] * TS : 0.0f;

  float4 st = reinterpret_cast<const float4*>(x)[env];
  const float r0 = st.w;
  float p = st.x, v = st.y, u = st.z;
  float racc = 0.0f;   // sum of u^2 over live steps

  unsigned long long live = __ballot(true);

  for (int stp = 0; stp < MAX_STEPS; ++stp) {
    float p1 = fmaxf(p, MIN_P);
    float v1 = (p <= MIN_P) ? 0.0f : v;

    // cos(3*p1): v_cos takes revolutions; independent of the MLP chain.
    float c = __builtin_amdgcn_cosf(p1 * 0.47746482927568601f);

    // Layer 1 (relu) + layer-2 partial dot, seeded with b2 on lane 0.
    float h0 = fmaxf(fmaf(v1, w1b[0], fmaf(p1, w1a[0], b1r[0])), 0.0f);
    float h1 = fmaxf(fmaf(v1, w1b[1], fmaf(p1, w1a[1], b1r[1])), 0.0f);
    float h2 = fmaxf(fmaf(v1, w1b[2], fmaf(p1, w1a[2], b1r[2])), 0.0f);
    float h3 = fmaxf(fmaf(v1, w1b[3], fmaf(p1, w1a[3], b1r[3])), 0.0f);
    float s = b2seed;
    s = fmaf(h0, w2r[0], s);
    s = fmaf(h1, w2r[1], s);
    s = fmaf(h2, w2r[2], s);
    s = fmaf(h3, w2r[3], s);

    // 16-lane butterfly; every lane ends with the full pre-scaled logit.
    s = dpp_add<0xB1>(s);     // quad_perm [1,0,3,2] : + lane^1
    s = dpp_add<0x4E>(s);     // quad_perm [2,3,0,1] : + lane^2
    s = dpp_add<0x141>(s);    // row_half_mirror    : + lane^(4..7)
    s = dpp_add<0x140>(s);    // row_mirror         : + lane^(8..15)

    // tanh, sign-free: 1 - 2/(exp2(s)+1); exact at both saturations.
    float e  = __builtin_amdgcn_exp2f(s);
    float u1 = fmaf(-2.0f, __builtin_amdgcn_rcpf(e + 1.0f), 1.0f);

    float v2 = fmaf(-0.0025f, c, fmaf(0.0015f, u1, v1));
    v2 = __builtin_amdgcn_fmed3f(v2, MIN_V, MAX_V);

    // Unconditional state update (write-at-crossing).
    p = p1 + v2;
    v = v2;
    u = u1;
    racc = fmaf(u1, u1, racc);

    // Newly-crossed envs commit their final row immediately.
    unsigned long long crossed = __ballot(p > GOAL_P) & live;
    if (crossed) {                        // wave-uniform, rarely taken
      live &= ~crossed;
      if (((crossed >> lane) & 1ull) && sub == 0) {
        float rout = fmaf(-0.1f, racc, r0) + 100.0f;
        reinterpret_cast<float4*>(out)[env] = make_float4(p, v, u, rout);
      }
      if (!live) return;                  // all 4 envs in wave committed
    }
  }

  // Envs that never crossed within MAX_STEPS: no +100.
  if (((live >> lane) & 1ull) && sub == 0) {
    float rout = fmaf(-0.1f, racc, r0);
    reinterpret_cast<float4*>(out)[env] = make_float4(p, v, u, rout);
  }
}

extern "C" void kernel_launch(void* const* d_in, const int* in_sizes, int n_in,
                              void* d_out, int out_size, void* d_ws, size_t ws_size,
                              hipStream_t stream) {
  const float* x  = (const float*)d_in[0];
  const float* w1 = (const float*)d_in[1];
  const float* b1 = (const float*)d_in[2];
  const float* w2 = (const float*)d_in[3];
  const float* b2 = (const float*)d_in[4];
  float* out = (float*)d_out;

  constexpr int threads = B * KL;  // 131072 -> 2048 waves -> 2 waves/SIMD
  mc_kernel<<<threads / 256, 256, 0, stream>>>(x, w1, b1, w2, b2, out);
}